// Round 1
// 2312.809 us; speedup vs baseline: 1.6137x; 1.6137x over previous
//
#include <hip/hip_runtime.h>
#include <math.h>

// Problem constants
#define BB   64
#define LL   720
#define CC   512
#define FF   361
#define KTOP 20

// ---------------------------------------------------------------------------
// Generic batched tile transpose: in (z, R, Cc) -> out (z, Cc, R)
// grid: (ceil(Cc/32), ceil(R/32), batch), block (32,8)
// ---------------------------------------------------------------------------
__global__ __launch_bounds__(256) void transpose_kernel(
    const float* __restrict__ in, float* __restrict__ out,
    int R, int Cc, long sIn, long sOut) {
  __shared__ float tile[32][33];
  const float* inp = in + (long)blockIdx.z * sIn;
  float* outp = out + (long)blockIdx.z * sOut;
  int r0 = blockIdx.y * 32, c0 = blockIdx.x * 32;
  int tx = threadIdx.x, ty = threadIdx.y;
#pragma unroll
  for (int i = 0; i < 4; ++i) {
    int r = r0 + ty + 8 * i, c = c0 + tx;
    if (r < R && c < Cc) tile[ty + 8 * i][tx] = inp[(long)r * Cc + c];
  }
  __syncthreads();
#pragma unroll
  for (int i = 0; i < 4; ++i) {
    int c = c0 + ty + 8 * i, r = r0 + tx;
    if (c < Cc && r < R) outp[(long)c * R + r] = tile[tx][ty + 8 * i];
  }
}

// ---------------------------------------------------------------------------
// residual[b,l,c] = x[b,l,c] - xfilt[b,c,l]   (transpose-subtract)
// grid: (16, 23, 64), block (32,8)
// ---------------------------------------------------------------------------
__global__ __launch_bounds__(256) void residual_kernel(
    const float* __restrict__ x, const float* __restrict__ xf,
    float* __restrict__ out) {
  __shared__ float tile[32][33];
  int b = blockIdx.z;
  const float* xfp = xf + (long)b * CC * LL;
  int c0 = blockIdx.x * 32, l0 = blockIdx.y * 32;
  int tx = threadIdx.x, ty = threadIdx.y;
#pragma unroll
  for (int i = 0; i < 4; ++i) {
    int c = c0 + ty + 8 * i, l = l0 + tx;
    if (l < LL) tile[ty + 8 * i][tx] = xfp[(long)c * LL + l];
  }
  __syncthreads();
  long xbase = (long)b * LL * CC;
#pragma unroll
  for (int i = 0; i < 4; ++i) {
    int l = l0 + ty + 8 * i, c = c0 + tx;
    if (l < LL) {
      long off = xbase + (long)l * CC + c;
      out[off] = x[off] - tile[tx][ty + 8 * i];
    }
  }
}

// ---------------------------------------------------------------------------
// Per-series DFT (361 freqs) + top-20 magnitude filter + reconstruction.
//
// v2: table-free hot loop. The old version did 4x ds_read_b64 per t-step at
// per-lane index (f*t)%720 -> 7.4e8 LDS bank-conflict cycles (~39% of kernel
// time) plus ~1.3ms of raw b64 LDS traffic. Now each thread owns one
// frequency SLOT f in [0,180] and advances (cos,sin) by an f64 rotation
// recurrence (drift ~1e-13 over 360 steps, far below the ~1e-6 rank-boundary
// gaps, so top-k ranking still matches the reference).
//
// Frequency-pair symmetry: for g = 360-f,
//   cos(g*t*W0) = (-1)^t cos(f*t*W0),  sin(g*t*W0) = -(-1)^t sin(f*t*W0)
// so with even/odd-t split accumulators (A/B):
//   Re[f] = x0 + (-1)^f x360 + Are + Bre     Im[f] = -(Aim + Bim)
//   Re[g] = x0 + (-1)^f x360 + Are - Bre     Im[g] =   Aim - Bim
// One rotation chain serves both freqs: 6 f64 FMA-class ops / t / slot for
// 2 frequencies => 1.28e10 FMA total (~326us floor at 78.6 TF f64).
// Only broadcast (conflict-free) LDS reads remain in the hot loop.
//
// One block of 192 threads (181 active slots) per (b,c) series.
// ---------------------------------------------------------------------------
__global__ __launch_bounds__(192) void dft_topk_kernel(
    const float* __restrict__ xt, float* __restrict__ xfilt) {
  __shared__ float  sx[720];
  __shared__ double ct[720];    // cos(j*2pi/720); sin(k*2pi/720)=ct[(k+540)%720]
  __shared__ double se[360];    // e[t]=x[t]+x[720-t], t=1..359
  __shared__ double so[360];    // o[t]=x[t]-x[720-t]
  __shared__ double sre[361];
  __shared__ double sim[361];
  __shared__ double smag[361];
  __shared__ int    ssel[KTOP];
  __shared__ double swv[3];
  __shared__ int    swi[3];

  const int tid = threadIdx.x;
  const long base = (long)blockIdx.x * LL;

  for (int t = tid; t < LL; t += 192) sx[t] = xt[base + t];
  const double W0d = 8.7266462599716478846e-3;  // 2*pi/720
  for (int j = tid; j < 720; j += 192) ct[j] = cos((double)j * W0d);
  __syncthreads();
  for (int t = tid + 1; t < 360; t += 192) {
    double xa = (double)sx[t], xb = (double)sx[LL - t];
    se[t] = xa + xb;
    so[t] = xa - xb;
  }
  __syncthreads();

  const double x0   = (double)sx[0];
  const double x360 = (double)sx[360];

  const int f = tid;
  if (f <= 180) {
    const double ca = ct[f];
    int fs = f + 540; if (fs >= 720) fs -= 720;
    const double sa = ct[fs];
    double c = ca, s = sa;              // twiddle at t=1
    double Are = 0.0, Aim = 0.0, Bre = 0.0, Bim = 0.0;
    for (int i = 0; i < 179; ++i) {
      const int to = 2 * i + 1;
      // t odd
      Bre = fma(se[to], c, Bre);
      Bim = fma(so[to], s, Bim);
      double c1 = fma(c, ca, -(s * sa));
      double s1 = fma(s, ca,  (c * sa));
      // t even
      Are = fma(se[to + 1], c1, Are);
      Aim = fma(so[to + 1], s1, Aim);
      c = fma(c1, ca, -(s1 * sa));
      s = fma(s1, ca,  (c1 * sa));
    }
    // t = 359 (odd)
    Bre = fma(se[359], c, Bre);
    Bim = fma(so[359], s, Bim);

    const double xe = (f & 1) ? (x0 - x360) : (x0 + x360);
    double ref = xe + Are + Bre;
    double imf = -(Aim + Bim);
    sre[f] = ref; sim[f] = imf; smag[f] = ref * ref + imf * imf;
    if (f < 180) {
      const int g = 360 - f;
      double reg = xe + Are - Bre;
      double img = Aim - Bim;
      sre[g] = reg; sim[g] = img; smag[g] = reg * reg + img * img;
    }
  }
  __syncthreads();

  // top-20 by repeated argmax (ties -> lower index, matching lax.top_k)
  const int f2 = tid + 192;
  const bool h2 = (f2 < FF);
  for (int it = 0; it < KTOP; ++it) {
    double v = smag[tid]; int bi = tid;
    if (h2) {
      double v2 = smag[f2];
      if (v2 > v) { v = v2; bi = f2; }   // f2 > tid, so tie keeps lower idx
    }
#pragma unroll
    for (int off = 32; off > 0; off >>= 1) {
      double ov = __shfl_down(v, off);
      int oi = __shfl_down(bi, off);
      if (ov > v || (ov == v && oi < bi)) { v = ov; bi = oi; }
    }
    if ((tid & 63) == 0) { swv[tid >> 6] = v; swi[tid >> 6] = bi; }
    __syncthreads();
    if (tid == 0) {
      double bv = swv[0]; int bb = swi[0];
      for (int w = 1; w < 3; ++w) {
        if (swv[w] > bv || (swv[w] == bv && swi[w] < bb)) { bv = swv[w]; bb = swi[w]; }
      }
      ssel[it] = bb;
      smag[bb] = -1.0;
    }
    __syncthreads();
  }

  // reconstruct: x_filt[t] = (1/L) * sum_f w_f (Re_f cos - Im_f sin)
  const double invL = 1.0 / 720.0;
  for (int t = tid; t < LL; t += 192) {
    double acc = 0.0;
#pragma unroll
    for (int it = 0; it < KTOP; ++it) {
      int fk = ssel[it];
      int k = (fk * t) % LL;
      int ks = k + 540; if (ks >= 720) ks -= 720;
      double cv = ct[k];
      double sv = ct[ks];
      double w = (fk == 0 || fk == 360) ? 1.0 : 2.0;
      acc += w * (sre[fk] * cv - sim[fk] * sv);
    }
    xfilt[base + t] = (float)(acc * invL);
  }
}

// ---------------------------------------------------------------------------
// fp32 tiled GEMM: Cout = epilogue(A[M,K] @ W[K,N]).
// BM=BN=64, BK=16, 256 threads, 4x4 acc per thread.
// EPI: 0 = store (acc+bias)
//      1 = store relu(acc+bias)
//      2 = store relu(acc+bias+Cin)
//      3 = store Cin + relu(acc+bias)
// BIASM: 0 none, 1 per-column, 2 per-row
// grid: (N/64, ceil(M/64), batch); strides sA/sW/sC applied per blockIdx.z.
// ---------------------------------------------------------------------------
template <int EPI, int BIASM>
__global__ __launch_bounds__(256) void gemm_f32(
    const float* __restrict__ A, const float* __restrict__ W,
    const float* __restrict__ bias, const float* __restrict__ Cin,
    float* __restrict__ Cout, int M, int N, int K,
    long sA, long sW, long sC) {
  __shared__ float As[16][68];
  __shared__ float Ws[16][68];
  A += (long)blockIdx.z * sA;
  W += (long)blockIdx.z * sW;
  Cin += (long)blockIdx.z * sC;
  Cout += (long)blockIdx.z * sC;
  const int m0 = blockIdx.y * 64, n0 = blockIdx.x * 64;
  const int tid = threadIdx.x;
  const int tx = tid & 15, ty = tid >> 4;
  const int arow = tid >> 2, ac = (tid & 3) * 4;
  const int wrow = tid >> 4, wc = (tid & 15) * 4;

  float acc[4][4] = {};
  for (int k0 = 0; k0 < K; k0 += 16) {
    float4 av;
    int gr = m0 + arow;
    if (gr < M) av = *(const float4*)&A[(long)gr * K + k0 + ac];
    else        av = make_float4(0.f, 0.f, 0.f, 0.f);
    float4 wv = *(const float4*)&W[(long)(k0 + wrow) * N + n0 + wc];
    __syncthreads();
    As[ac + 0][arow] = av.x; As[ac + 1][arow] = av.y;
    As[ac + 2][arow] = av.z; As[ac + 3][arow] = av.w;
    *(float4*)&Ws[wrow][wc] = wv;
    __syncthreads();
#pragma unroll
    for (int kk = 0; kk < 16; ++kk) {
      float4 a = *(const float4*)&As[kk][ty * 4];
      float4 b = *(const float4*)&Ws[kk][tx * 4];
      float aa[4] = {a.x, a.y, a.z, a.w};
      float bb[4] = {b.x, b.y, b.z, b.w};
#pragma unroll
      for (int i = 0; i < 4; ++i)
#pragma unroll
        for (int j = 0; j < 4; ++j)
          acc[i][j] = fmaf(aa[i], bb[j], acc[i][j]);
    }
  }

#pragma unroll
  for (int i = 0; i < 4; ++i) {
    int r = m0 + ty * 4 + i;
    if (r >= M) continue;
    float rb = (BIASM == 2) ? bias[r] : 0.f;
#pragma unroll
    for (int j = 0; j < 4; ++j) {
      int cix = n0 + tx * 4 + j;
      float v = acc[i][j];
      if (BIASM == 1) v += bias[cix];
      if (BIASM == 2) v += rb;
      long off = (long)r * N + cix;
      if (EPI == 0) Cout[off] = v;
      else if (EPI == 1) Cout[off] = fmaxf(v, 0.f);
      else if (EPI == 2) Cout[off] = fmaxf(v + Cin[off], 0.f);
      else Cout[off] = Cin[off] + fmaxf(v, 0.f);
    }
  }
}

// ---------------------------------------------------------------------------
extern "C" void kernel_launch(void* const* d_in, const int* in_sizes, int n_in,
                              void* d_out, int out_size, void* d_ws, size_t ws_size,
                              hipStream_t stream) {
  const float* x      = (const float*)d_in[0];
  const float* w_freq = (const float*)d_in[1];
  const float* b_freq = (const float*)d_in[2];
  const float* w_all1 = (const float*)d_in[3];
  const float* b_all1 = (const float*)d_in[4];
  const float* w_all2 = (const float*)d_in[5];
  const float* b_all2 = (const float*)d_in[6];
  const float* w_time = (const float*)d_in[7];
  const float* b_time = (const float*)d_in[8];
  const float* w_chan = (const float*)d_in[9];
  const float* b_chan = (const float*)d_in[10];
  const float* w_proj = (const float*)d_in[11];
  const float* b_proj = (const float*)d_in[12];

  float* out0 = (float*)d_out;                       // residual (64,720,512)
  float* out1 = out0 + (size_t)BB * LL * CC;         // pred     (64,720,512)

  // workspace layout (floats). Peak ~214.6 MB.
  float* ws  = (float*)d_ws;
  float* XT  = ws;                    // (64,512,720)  23,592,960
  float* XF  = XT + 23592960;         // (64,512,720)  23,592,960
  float* H   = XF + 23592960;         // (32768,64)     2,097,152
  float* A1  = H + 2097152;           // (32768,128)    4,194,304
  float* WPT = A1 + 4194304;          // (720,256)        184,320
  float* Z   = XF;                    // reuse XF after h-GEMM: (32768,256)
  float* T   = XF + 8388608;          // (32768,256)
  float* TT  = XT;                    // reuse XT after a1-GEMM: (64,256,512)
  float* CO  = XT + 8388608;          // (64,256,512)

  dim3 tb(32, 8);

  // 1) x (b,720,512) -> XT (b,512,720)
  transpose_kernel<<<dim3(16, 23, BB), tb, 0, stream>>>(
      x, XT, LL, CC, (long)LL * CC, (long)LL * CC);
  // 2) w_proj (256,720) -> WPT (720,256)
  transpose_kernel<<<dim3(23, 8, 1), tb, 0, stream>>>(
      w_proj, WPT, 256, 720, 0, 0);
  // 3) per-series DFT + top-20 filter -> XF (b,512,720)
  dft_topk_kernel<<<BB * CC, 192, 0, stream>>>(XT, XF);
  // 4) residual = x - XF^T -> out0
  residual_kernel<<<dim3(16, 23, BB), tb, 0, stream>>>(x, XF, out0);
  // 5) h = relu(XF @ w_freq + b_freq)            (32768,720)x(720,64)
  gemm_f32<1, 1><<<dim3(1, 512, 1), 256, 0, stream>>>(
      XF, w_freq, b_freq, nullptr, H, 32768, 64, 720, 0, 0, 0);
  // 6) tmp = h @ w_all1[:64]                     (32768,64)x(64,128)
  gemm_f32<0, 0><<<dim3(2, 512, 1), 256, 0, stream>>>(
      H, w_all1, nullptr, nullptr, A1, 32768, 128, 64, 0, 0, 0);
  // 7) a1 = relu(tmp + XT @ w_all1[64:] + b_all1) (32768,720)x(720,128)
  gemm_f32<2, 1><<<dim3(2, 512, 1), 256, 0, stream>>>(
      XT, w_all1 + 64 * 128, b_all1, A1, A1, 32768, 128, 720, 0, 0, 0);
  // 8) z = a1 @ w_all2 + b_all2                  (32768,128)x(128,256)
  gemm_f32<0, 1><<<dim3(4, 512, 1), 256, 0, stream>>>(
      A1, w_all2, b_all2, nullptr, Z, 32768, 256, 128, 0, 0, 0);
  // 9) t = z + relu(z @ w_time + b_time)         (32768,256)x(256,256)
  gemm_f32<3, 1><<<dim3(4, 512, 1), 256, 0, stream>>>(
      Z, w_time, b_time, Z, T, 32768, 256, 256, 0, 0, 0);
  // 10) T (b,512,256) -> TT (b,256,512)
  transpose_kernel<<<dim3(8, 16, BB), tb, 0, stream>>>(
      T, TT, 512, 256, (long)512 * 256, (long)512 * 256);
  // 11) c = TT + relu(TT @ w_chan + b_chan)      (16384,512)x(512,512)
  gemm_f32<3, 1><<<dim3(8, 256, 1), 256, 0, stream>>>(
      TT, w_chan, b_chan, TT, CO, 16384, 512, 512, 0, 0, 0);
  // 12) pred[b,p,c] = WPT[p,:] @ CO[b,:,c] + b_proj[p]  (720,256)x(256,512) x64
  gemm_f32<0, 2><<<dim3(8, 12, BB), 256, 0, stream>>>(
      WPT, CO, b_proj, nullptr, out1, 720, 512, 256,
      0, (long)256 * 512, (long)LL * CC);
}

// Round 2
// 1516.363 us; speedup vs baseline: 2.4613x; 1.5252x over previous
//
#include <hip/hip_runtime.h>
#include <math.h>

// Problem constants
#define BB   64
#define LL   720
#define CC   512
#define FF   361
#define KTOP 20

// ---------------------------------------------------------------------------
// Generic batched tile transpose: in (z, R, Cc) -> out (z, Cc, R)
// grid: (ceil(Cc/32), ceil(R/32), batch), block (32,8)
// ---------------------------------------------------------------------------
__global__ __launch_bounds__(256) void transpose_kernel(
    const float* __restrict__ in, float* __restrict__ out,
    int R, int Cc, long sIn, long sOut) {
  __shared__ float tile[32][33];
  const float* inp = in + (long)blockIdx.z * sIn;
  float* outp = out + (long)blockIdx.z * sOut;
  int r0 = blockIdx.y * 32, c0 = blockIdx.x * 32;
  int tx = threadIdx.x, ty = threadIdx.y;
#pragma unroll
  for (int i = 0; i < 4; ++i) {
    int r = r0 + ty + 8 * i, c = c0 + tx;
    if (r < R && c < Cc) tile[ty + 8 * i][tx] = inp[(long)r * Cc + c];
  }
  __syncthreads();
#pragma unroll
  for (int i = 0; i < 4; ++i) {
    int c = c0 + ty + 8 * i, r = r0 + tx;
    if (c < Cc && r < R) outp[(long)c * R + r] = tile[tx][ty + 8 * i];
  }
}

// ---------------------------------------------------------------------------
// residual[b,l,c] = x[b,l,c] - xfilt[b,c,l]   (transpose-subtract)
// grid: (16, 23, 64), block (32,8)
// ---------------------------------------------------------------------------
__global__ __launch_bounds__(256) void residual_kernel(
    const float* __restrict__ x, const float* __restrict__ xf,
    float* __restrict__ out) {
  __shared__ float tile[32][33];
  int b = blockIdx.z;
  const float* xfp = xf + (long)b * CC * LL;
  int c0 = blockIdx.x * 32, l0 = blockIdx.y * 32;
  int tx = threadIdx.x, ty = threadIdx.y;
#pragma unroll
  for (int i = 0; i < 4; ++i) {
    int c = c0 + ty + 8 * i, l = l0 + tx;
    if (l < LL) tile[ty + 8 * i][tx] = xfp[(long)c * LL + l];
  }
  __syncthreads();
  long xbase = (long)b * LL * CC;
#pragma unroll
  for (int i = 0; i < 4; ++i) {
    int l = l0 + ty + 8 * i, c = c0 + tx;
    if (l < LL) {
      long off = xbase + (long)l * CC + c;
      out[off] = x[off] - tile[tx][ty + 8 * i];
    }
  }
}

// ---------------------------------------------------------------------------
// One-time twiddle table: ctd[j] = cos(j*2pi/720), f64. Shared by all dft
// blocks (removes 23.6M per-block cos() libcalls).
// ---------------------------------------------------------------------------
__global__ __launch_bounds__(256) void init_tw_kernel(double* __restrict__ ctd) {
  int j = blockIdx.x * 256 + threadIdx.x;
  const double W0d = 8.7266462599716478846e-3;  // 2*pi/720
  if (j < 720) ctd[j] = cos((double)j * W0d);
}

// ---------------------------------------------------------------------------
// Per-series DFT (361 freqs) + top-20 magnitude filter + reconstruction.
//
// v3: 4-frequency symmetry + barrier-free top-k + f32 reconstruction.
// Each thread slot f in [0,90] serves frequencies {f, 180-f, 180+f, 360-f}
// via ONE f64 rotation chain and t-mod-4 partial sums:
//   cos((180-f)tW0) = cos(t*pi/2)cos(ftW0) + sin(t*pi/2)sin(ftW0), etc.
// with cos/sin(t*pi/2) in {0,+-1}. Per 4 t's: 12 FMA + 16 rotation ops
// serving 4 freqs => 3.5 f64 ops/freq/t (was 6). Rotation drift ~1e-13
// over 360 steps, far below the ~1e-7 top-k rank-boundary gaps.
// Magnitudes stay f64 (ranking must match the fp64-exact path that passes);
// reconstruction is f32 with prescaled w*Re/L coefficients (error ~1e-6,
// threshold 0.1625).
// Two series per 192-thread block: lanes 0-90 series0, 96-186 series1.
// Top-k: wave0 (series0) and wave2 (series1) via shfl_xor butterfly,
// zero barriers inside the 20 argmax rounds. 4 __syncthreads total (was 44).
// ---------------------------------------------------------------------------
__global__ __launch_bounds__(192) void dft_topk_kernel(
    const float* __restrict__ xt, const double* __restrict__ ctd,
    float* __restrict__ xfilt) {
  __shared__ double seo[2][361][2];   // [series][t][{e,o}]; t=0 holds {x0,x360}; t=360 zero
  __shared__ float  ctf[720];         // f32 twiddles for reconstruction
  __shared__ float  sres[2][361];     // prescaled w*Re/L
  __shared__ float  sims[2][361];     // prescaled w*Im/L
  __shared__ int    ssel[2][KTOP];

  const int tid = threadIdx.x;
  const long ser0 = (long)blockIdx.x * 2;

  // fold: e[t]=x[t]+x[720-t], o[t]=x[t]-x[720-t]; t=0 stores {x0,x360}; t=360 zero-pad
  for (int p = tid; p < 722; p += 192) {
    int sp = (p >= 361) ? 1 : 0;
    int t = p - 361 * sp;
    const float* xs = xt + (ser0 + sp) * LL;
    double e, o;
    if (t == 0)       { e = (double)xs[0]; o = (double)xs[360]; }
    else if (t < 360) { double xa = (double)xs[t], xb = (double)xs[720 - t];
                        e = xa + xb; o = xa - xb; }
    else              { e = 0.0; o = 0.0; }
    seo[sp][t][0] = e; seo[sp][t][1] = o;
  }
  for (int j = tid; j < 720; j += 192) ctf[j] = (float)ctd[j];
  __syncthreads();

  const int s = (tid >= 96) ? 1 : 0;
  const int f = tid - 96 * s;     // slot in [0,95]; active if <= 90
  const bool act = (f <= 90);

  const double ca = ctd[f];           // cos(f*W0)
  const double sa = ctd[f + 540];     // sin(f*W0); f+540 <= 635 < 720
  double c = ca, sn = sa;             // twiddle at t=1

  // partial sums over t mod 4 (t = 1..359; t=360 term is zero-padded)
  double EC0 = 0, EC1 = 0, EC2 = 0, EC3 = 0;
  double ESd = 0;                     // ES1 - ES3 (signs folded into FMA)
  double OCd = 0;                     // OC1 - OC3
  double OS0 = 0, OS1 = 0, OS2 = 0, OS3 = 0;

  for (int u = 0; u < 90; ++u) {
    const int t = 4 * u + 1;
    double e1 = seo[s][t][0],     o1 = seo[s][t][1];
    double e2 = seo[s][t + 1][0], o2 = seo[s][t + 1][1];
    double e3 = seo[s][t + 2][0], o3 = seo[s][t + 2][1];
    double e4 = seo[s][t + 3][0], o4 = seo[s][t + 3][1];
    // t ≡ 1 (mod 4)
    EC1 = fma(e1, c, EC1);  ESd = fma(e1, sn, ESd);
    OCd = fma(o1, c, OCd);  OS1 = fma(o1, sn, OS1);
    double c2 = fma(c, ca, -(sn * sa)), s2 = fma(sn, ca, c * sa);
    // t ≡ 2
    EC2 = fma(e2, c2, EC2); OS2 = fma(o2, s2, OS2);
    double c3 = fma(c2, ca, -(s2 * sa)), s3 = fma(s2, ca, c2 * sa);
    // t ≡ 3
    EC3 = fma(e3, c3, EC3); ESd = fma(e3, -s3, ESd);
    OCd = fma(o3, -c3, OCd); OS3 = fma(o3, s3, OS3);
    double c4 = fma(c3, ca, -(s3 * sa)), s4 = fma(s3, ca, c3 * sa);
    // t ≡ 0
    EC0 = fma(e4, c4, EC0); OS0 = fma(o4, s4, OS0);
    double c5 = fma(c4, ca, -(s4 * sa)), s5 = fma(s4, ca, c4 * sa);
    c = c5; sn = s5;
  }

  // combine into the 4 frequencies (read x0/x360 BEFORE seo gets reused)
  double reF = 0, imF = 0, reG1 = 0, imG1 = 0, reG2 = 0, imG2 = 0, reG3 = 0, imG3 = 0;
  if (act) {
    double x0 = seo[s][0][0], x360 = seo[s][0][1];
    double xe = (f & 1) ? (x0 - x360) : (x0 + x360);
    reF  = xe + ((EC0 + EC1) + (EC2 + EC3));
    imF  = -((OS0 + OS1) + (OS2 + OS3));
    reG3 = xe + ((EC0 - EC1) + (EC2 - EC3));
    imG3 = (OS0 - OS1) + (OS2 - OS3);
    double ecd = EC0 - EC2, osd = OS0 - OS2;
    reG1 = xe + ecd + ESd;
    imG1 = osd - OCd;
    reG2 = xe + ecd - ESd;
    imG2 = -osd - OCd;
  }
  __syncthreads();   // all hot-loop reads of seo done; safe to alias as smag

  double* mg = &seo[s][0][0];   // 361 f64 magnitudes, reusing seo storage
  if (act) {
    const double invL = 1.0 / 720.0;
    double s0 = (f == 0) ? invL : 2.0 * invL;   // w=1 only at f==0 / 360
    const double s2d = 2.0 * invL;
    int i3 = 360 - f, i1 = 180 - f, i2 = 180 + f;
    mg[f]  = reF * reF + imF * imF;
    sres[s][f]  = (float)(reF * s0);  sims[s][f]  = (float)(imF * s0);
    mg[i3] = reG3 * reG3 + imG3 * imG3;
    sres[s][i3] = (float)(reG3 * s0); sims[s][i3] = (float)(imG3 * s0);
    mg[i1] = reG1 * reG1 + imG1 * imG1;
    sres[s][i1] = (float)(reG1 * s2d); sims[s][i1] = (float)(imG1 * s2d);
    mg[i2] = reG2 * reG2 + imG2 * imG2;
    sres[s][i2] = (float)(reG2 * s2d); sims[s][i2] = (float)(imG2 * s2d);
  }
  __syncthreads();

  // top-20: wave0 -> series0, wave2 -> series1; pure shfl, no barriers.
  // ties -> lower index (matching lax.top_k): ascending local scan with
  // strict >, cross-lane (ov>v)||(ov==v && oi<bi).
  const int wv = tid >> 6, ln = tid & 63;
  if (wv != 1) {
    const int sw = wv >> 1;
    const double* mgw = &seo[sw][0][0];
    double val[6];
#pragma unroll
    for (int j = 0; j < 6; ++j) {
      int idx = ln + 64 * j;
      val[j] = (idx < FF) ? mgw[idx] : -2.0;
    }
    for (int it = 0; it < KTOP; ++it) {
      double v = val[0]; int bi = ln;
#pragma unroll
      for (int j = 1; j < 6; ++j) {
        if (val[j] > v) { v = val[j]; bi = ln + 64 * j; }
      }
#pragma unroll
      for (int off = 1; off < 64; off <<= 1) {
        double ov = __shfl_xor(v, off);
        int oi = __shfl_xor(bi, off);
        if (ov > v || (ov == v && oi < bi)) { v = ov; bi = oi; }
      }
      if (ln == 0) ssel[sw][it] = bi;
      if ((bi & 63) == ln) val[bi >> 6] = -2.0;   // remove winner
    }
  }
  __syncthreads();

  // reconstruct (f32): x_filt[t] = sum_sel (sres*cos - sims*sin)
  for (int p = tid; p < 1440; p += 192) {
    int sp = (p >= 720) ? 1 : 0;
    int t = p - 720 * sp;
    float acc = 0.f;
#pragma unroll
    for (int it = 0; it < KTOP; ++it) {
      int fk = ssel[sp][it];
      int k = (fk * t) % 720;
      int ks = k + 540; if (ks >= 720) ks -= 720;
      acc = fmaf(sres[sp][fk], ctf[k], acc);
      acc = fmaf(-sims[sp][fk], ctf[ks], acc);
    }
    xfilt[(ser0 + sp) * LL + t] = acc;
  }
}

// ---------------------------------------------------------------------------
// fp32 tiled GEMM: Cout = epilogue(A[M,K] @ W[K,N]).
// BM=BN=64, BK=16, 256 threads, 4x4 acc per thread.
// EPI: 0 = store (acc+bias)
//      1 = store relu(acc+bias)
//      2 = store relu(acc+bias+Cin)
//      3 = store Cin + relu(acc+bias)
// BIASM: 0 none, 1 per-column, 2 per-row
// grid: (N/64, ceil(M/64), batch); strides sA/sW/sC applied per blockIdx.z.
// ---------------------------------------------------------------------------
template <int EPI, int BIASM>
__global__ __launch_bounds__(256) void gemm_f32(
    const float* __restrict__ A, const float* __restrict__ W,
    const float* __restrict__ bias, const float* __restrict__ Cin,
    float* __restrict__ Cout, int M, int N, int K,
    long sA, long sW, long sC) {
  __shared__ float As[16][68];
  __shared__ float Ws[16][68];
  A += (long)blockIdx.z * sA;
  W += (long)blockIdx.z * sW;
  Cin += (long)blockIdx.z * sC;
  Cout += (long)blockIdx.z * sC;
  const int m0 = blockIdx.y * 64, n0 = blockIdx.x * 64;
  const int tid = threadIdx.x;
  const int tx = tid & 15, ty = tid >> 4;
  const int arow = tid >> 2, ac = (tid & 3) * 4;
  const int wrow = tid >> 4, wc = (tid & 15) * 4;

  float acc[4][4] = {};
  for (int k0 = 0; k0 < K; k0 += 16) {
    float4 av;
    int gr = m0 + arow;
    if (gr < M) av = *(const float4*)&A[(long)gr * K + k0 + ac];
    else        av = make_float4(0.f, 0.f, 0.f, 0.f);
    float4 wv = *(const float4*)&W[(long)(k0 + wrow) * N + n0 + wc];
    __syncthreads();
    As[ac + 0][arow] = av.x; As[ac + 1][arow] = av.y;
    As[ac + 2][arow] = av.z; As[ac + 3][arow] = av.w;
    *(float4*)&Ws[wrow][wc] = wv;
    __syncthreads();
#pragma unroll
    for (int kk = 0; kk < 16; ++kk) {
      float4 a = *(const float4*)&As[kk][ty * 4];
      float4 b = *(const float4*)&Ws[kk][tx * 4];
      float aa[4] = {a.x, a.y, a.z, a.w};
      float bb[4] = {b.x, b.y, b.z, b.w};
#pragma unroll
      for (int i = 0; i < 4; ++i)
#pragma unroll
        for (int j = 0; j < 4; ++j)
          acc[i][j] = fmaf(aa[i], bb[j], acc[i][j]);
    }
  }

#pragma unroll
  for (int i = 0; i < 4; ++i) {
    int r = m0 + ty * 4 + i;
    if (r >= M) continue;
    float rb = (BIASM == 2) ? bias[r] : 0.f;
#pragma unroll
    for (int j = 0; j < 4; ++j) {
      int cix = n0 + tx * 4 + j;
      float v = acc[i][j];
      if (BIASM == 1) v += bias[cix];
      if (BIASM == 2) v += rb;
      long off = (long)r * N + cix;
      if (EPI == 0) Cout[off] = v;
      else if (EPI == 1) Cout[off] = fmaxf(v, 0.f);
      else if (EPI == 2) Cout[off] = fmaxf(v + Cin[off], 0.f);
      else Cout[off] = Cin[off] + fmaxf(v, 0.f);
    }
  }
}

// ---------------------------------------------------------------------------
extern "C" void kernel_launch(void* const* d_in, const int* in_sizes, int n_in,
                              void* d_out, int out_size, void* d_ws, size_t ws_size,
                              hipStream_t stream) {
  const float* x      = (const float*)d_in[0];
  const float* w_freq = (const float*)d_in[1];
  const float* b_freq = (const float*)d_in[2];
  const float* w_all1 = (const float*)d_in[3];
  const float* b_all1 = (const float*)d_in[4];
  const float* w_all2 = (const float*)d_in[5];
  const float* b_all2 = (const float*)d_in[6];
  const float* w_time = (const float*)d_in[7];
  const float* b_time = (const float*)d_in[8];
  const float* w_chan = (const float*)d_in[9];
  const float* b_chan = (const float*)d_in[10];
  const float* w_proj = (const float*)d_in[11];
  const float* b_proj = (const float*)d_in[12];

  float* out0 = (float*)d_out;                       // residual (64,720,512)
  float* out1 = out0 + (size_t)BB * LL * CC;         // pred     (64,720,512)

  // workspace layout (floats). Peak ~214.6 MB.
  float* ws  = (float*)d_ws;
  float* XT  = ws;                    // (64,512,720)  23,592,960
  float* XF  = XT + 23592960;         // (64,512,720)  23,592,960
  float* H   = XF + 23592960;         // (32768,64)     2,097,152
  float* A1  = H + 2097152;           // (32768,128)    4,194,304
  float* WPT = A1 + 4194304;          // (720,256)        184,320
  float* Z   = XF;                    // reuse XF after h-GEMM: (32768,256)
  float* T   = XF + 8388608;          // (32768,256)
  float* TT  = XT;                    // reuse XT after a1-GEMM: (64,256,512)
  float* CO  = XT + 8388608;          // (64,256,512)
  // twiddle table aliases H: H is first written at step 5, CTD consumed at step 3.
  double* CTD = (double*)H;           // 720 doubles

  dim3 tb(32, 8);

  // 0) f64 twiddle table (once per launch; tiny)
  init_tw_kernel<<<3, 256, 0, stream>>>(CTD);
  // 1) x (b,720,512) -> XT (b,512,720)
  transpose_kernel<<<dim3(16, 23, BB), tb, 0, stream>>>(
      x, XT, LL, CC, (long)LL * CC, (long)LL * CC);
  // 2) w_proj (256,720) -> WPT (720,256)
  transpose_kernel<<<dim3(23, 8, 1), tb, 0, stream>>>(
      w_proj, WPT, 256, 720, 0, 0);
  // 3) per-series DFT + top-20 filter -> XF (b,512,720); 2 series/block
  dft_topk_kernel<<<BB * CC / 2, 192, 0, stream>>>(XT, CTD, XF);
  // 4) residual = x - XF^T -> out0
  residual_kernel<<<dim3(16, 23, BB), tb, 0, stream>>>(x, XF, out0);
  // 5) h = relu(XF @ w_freq + b_freq)            (32768,720)x(720,64)
  gemm_f32<1, 1><<<dim3(1, 512, 1), 256, 0, stream>>>(
      XF, w_freq, b_freq, nullptr, H, 32768, 64, 720, 0, 0, 0);
  // 6) tmp = h @ w_all1[:64]                     (32768,64)x(64,128)
  gemm_f32<0, 0><<<dim3(2, 512, 1), 256, 0, stream>>>(
      H, w_all1, nullptr, nullptr, A1, 32768, 128, 64, 0, 0, 0);
  // 7) a1 = relu(tmp + XT @ w_all1[64:] + b_all1) (32768,720)x(720,128)
  gemm_f32<2, 1><<<dim3(2, 512, 1), 256, 0, stream>>>(
      XT, w_all1 + 64 * 128, b_all1, A1, A1, 32768, 128, 720, 0, 0, 0);
  // 8) z = a1 @ w_all2 + b_all2                  (32768,128)x(128,256)
  gemm_f32<0, 1><<<dim3(4, 512, 1), 256, 0, stream>>>(
      A1, w_all2, b_all2, nullptr, Z, 32768, 256, 128, 0, 0, 0);
  // 9) t = z + relu(z @ w_time + b_time)         (32768,256)x(256,256)
  gemm_f32<3, 1><<<dim3(4, 512, 1), 256, 0, stream>>>(
      Z, w_time, b_time, Z, T, 32768, 256, 256, 0, 0, 0);
  // 10) T (b,512,256) -> TT (b,256,512)
  transpose_kernel<<<dim3(8, 16, BB), tb, 0, stream>>>(
      T, TT, 512, 256, (long)512 * 256, (long)512 * 256);
  // 11) c = TT + relu(TT @ w_chan + b_chan)      (16384,512)x(512,512)
  gemm_f32<3, 1><<<dim3(8, 256, 1), 256, 0, stream>>>(
      TT, w_chan, b_chan, TT, CO, 16384, 512, 512, 0, 0, 0);
  // 12) pred[b,p,c] = WPT[p,:] @ CO[b,:,c] + b_proj[p]  (720,256)x(256,512) x64
  gemm_f32<0, 2><<<dim3(8, 12, BB), 256, 0, stream>>>(
      WPT, CO, b_proj, nullptr, out1, 720, 512, 256,
      0, (long)256 * 512, (long)LL * CC);
}